// Round 1
// baseline (489.148 us; speedup 1.0000x reference)
//
#include <hip/hip_runtime.h>
#include <hip/hip_bf16.h>
#include <math.h>

typedef __bf16 bf16x8 __attribute__((ext_vector_type(8)));
typedef float  f32x4  __attribute__((ext_vector_type(4)));

#define CDIM 1024
#define DDIM 64
#define NB   16384
#define NROWS 65536

// float -> bf16 bits, round-to-nearest-even (finite inputs)
__device__ __forceinline__ unsigned short f2bf(float x){
  unsigned int u = __float_as_uint(x);
  unsigned int lsb = (u >> 16) & 1u;
  u += 0x7fffu + lsb;
  return (unsigned short)(u >> 16);
}

// ---------------- K0: transpose Wd -> bf16 Wt[n][k], and seln = l2norm(sel) ---------
__global__ void dsa_prep(const float* __restrict__ Wd, const float* __restrict__ tf,
                         unsigned short* __restrict__ Wt, float* __restrict__ seln){
  int bb = blockIdx.x, tid = threadIdx.x;
  if (bb < 256){
    int e = bb*256 + tid;            // 0..65535
    int kk = e >> 6, n = e & 63;     // Wd[kk][n]
    Wt[n*CDIM + kk] = f2bf(Wd[e]);
  } else {
    int w = tid >> 6, lane = tid & 63;   // wave w = batch w
    float x = tf[w*(20*512) + lane];     // text_features[b,0,lane]
    float sq = x*x;
    #pragma unroll
    for (int m=1; m<64; m<<=1) sq += __shfl_xor(sq, m);
    float nrm = fmaxf(sqrtf(sq), 1e-12f);
    seln[w*64 + lane] = x / nrm;
  }
}

// ---------------- K2: fused  out=X+g*bu  |  a=gelu(X@Wd+bd)  |  scores --------------
__global__ __launch_bounds__(256) void dsa_main(
    const float* __restrict__ X, const unsigned short* __restrict__ Wt,
    const float* __restrict__ bd, const float* __restrict__ bu,
    const float* __restrict__ gam, const float* __restrict__ seln,
    float* __restrict__ out, float* __restrict__ a_out, float* __restrict__ scores)
{
  __shared__ __align__(16) unsigned short As[2][4096];
  __shared__ __align__(16) unsigned short Bs[2][4096];
  const int tid  = threadIdx.x;
  const int lane = tid & 63;
  const int w    = tid >> 6;
  const int row0 = blockIdx.x * 64;
  const int batch = row0 >> 14;
  const float gamma = gam[0];

  const int kq   = tid & 15;   // A staging: k-quad (4 floats)
  const int rowb = tid >> 4;   // A staging: row base 0..15
  const int bn0  = tid >> 3;   // B staging: n 0..31 (+32)
  const int bko  = (tid & 7) * 8;

  float4 xr[4];
  uint4  br[2];

  auto loadStage = [&](int t){
    const int c0 = t*64 + kq*4;
    #pragma unroll
    for (int i=0;i<4;i++){
      int r = rowb + 16*i;
      xr[i] = *(const float4*)(X + (size_t)(row0+r)*CDIM + c0);
    }
    #pragma unroll
    for (int i=0;i<2;i++){
      int n = bn0 + 32*i;
      br[i] = *(const uint4*)(Wt + n*CDIM + t*64 + bko);
    }
  };
  auto writeStage = [&](int buf, int t){
    const int c0 = t*64 + kq*4;
    float4 bu4 = *(const float4*)(bu + c0);
    #pragma unroll
    for (int i=0;i<4;i++){
      int r = rowb + 16*i;
      float4 x = xr[i];
      float4 o4;
      o4.x = x.x + gamma*bu4.x; o4.y = x.y + gamma*bu4.y;
      o4.z = x.z + gamma*bu4.z; o4.w = x.w + gamma*bu4.w;
      *(float4*)(out + (size_t)(row0+r)*CDIM + c0) = o4;   // fused identity copy
      ushort4 u4;
      u4.x = f2bf(x.x); u4.y = f2bf(x.y); u4.z = f2bf(x.z); u4.w = f2bf(x.w);
      int off = (r*128 + kq*8) ^ ((r & 7) << 4);           // XOR swizzle (T2)
      *(ushort4*)((char*)(&As[buf][0]) + off) = u4;
    }
    #pragma unroll
    for (int i=0;i<2;i++){
      int n = bn0 + 32*i;
      int off = (n*128 + bko*2) ^ ((n & 7) << 4);
      *(uint4*)((char*)(&Bs[buf][0]) + off) = br[i];
    }
  };

  loadStage(0);
  writeStage(0, 0);
  __syncthreads();

  f32x4 acc[4] = {};
  int cur = 0;
  for (int t = 0; t < 16; ++t){
    if (t < 15) loadStage(t+1);
    const int arow = 16*w + (lane & 15);
    #pragma unroll
    for (int s=0;s<2;s++){
      int aoff = (arow*128 + s*64 + (lane>>4)*16) ^ ((arow & 7) << 4);
      bf16x8 av = *(const bf16x8*)((const char*)(&As[cur][0]) + aoff);
      #pragma unroll
      for (int j=0;j<4;j++){
        int bn = 16*j + (lane & 15);
        int boff = (bn*128 + s*64 + (lane>>4)*16) ^ ((bn & 7) << 4);
        bf16x8 bv = *(const bf16x8*)((const char*)(&Bs[cur][0]) + boff);
        acc[j] = __builtin_amdgcn_mfma_f32_16x16x32_bf16(av, bv, acc[j], 0,0,0);
      }
    }
    if (t < 15){ writeStage(cur^1, t+1); cur ^= 1; }
    __syncthreads();
  }

  // Epilogue: +bd, exact gelu, write a, fused l2norm-dot scores
  const float* selb = seln + batch*64;
  float ss[4] = {0,0,0,0}, dt[4] = {0,0,0,0};
  float gv[4][4];
  #pragma unroll
  for (int j=0;j<4;j++){
    int col = 16*j + (lane & 15);
    float bdc = bd[col];
    float sc  = selb[col];
    #pragma unroll
    for (int r=0;r<4;r++){
      float y = acc[j][r] + bdc;
      float g = 0.5f * y * (1.0f + erff(y * 0.70710678118654752f));
      gv[j][r] = g;
      ss[r] += g*g;
      dt[r] += g*sc;
    }
  }
  #pragma unroll
  for (int r=0;r<4;r++){
    int row = row0 + 16*w + 4*(lane>>4) + r;
    #pragma unroll
    for (int j=0;j<4;j++){
      int col = 16*j + (lane & 15);
      a_out[(size_t)row*DDIM + col] = gv[j][r];
    }
  }
  #pragma unroll
  for (int m=1;m<16;m<<=1){
    #pragma unroll
    for (int r=0;r<4;r++){
      ss[r] += __shfl_xor(ss[r], m);
      dt[r] += __shfl_xor(dt[r], m);
    }
  }
  if ((lane & 15) == 0){
    #pragma unroll
    for (int r=0;r<4;r++){
      int row = row0 + 16*w + 4*(lane>>4) + r;
      scores[row] = dt[r] / fmaxf(sqrtf(ss[r]), 1e-12f);
    }
  }
}

// ---------------- K3: per-batch top-64 (tournament) + ascending index sort ----------
__global__ __launch_bounds__(512) void dsa_topk(const float* __restrict__ scores,
                                                int* __restrict__ idxo){
  int b = blockIdx.x, tid = threadIdx.x;
  const float* s = scores + b*NB;
  float v[32];
  const int base = tid*32;
  #pragma unroll
  for (int i=0;i<32;i+=4){
    float4 f = *(const float4*)(s + base + i);
    v[i]=f.x; v[i+1]=f.y; v[i+2]=f.z; v[i+3]=f.w;
  }
  float cm = -3e38f; int ci = base;
  #pragma unroll
  for (int i=0;i<32;i++) if (v[i] > cm){ cm=v[i]; ci=base+i; }

  __shared__ float wv[8];
  __shared__ int   wi[8];
  __shared__ int   sbi;
  __shared__ int   sel[64];
  int lane = tid & 63, w = tid >> 6;

  for (int it=0; it<64; ++it){
    float bv = cm; int bi = ci;
    #pragma unroll
    for (int m=1;m<64;m<<=1){
      float ov = __shfl_xor(bv, m);
      int   oi = __shfl_xor(bi, m);
      if (ov > bv || (ov == bv && oi < bi)){ bv=ov; bi=oi; }
    }
    if (lane==0){ wv[w]=bv; wi[w]=bi; }
    __syncthreads();
    if (tid==0){
      float Bv = wv[0]; int Bi = wi[0];
      #pragma unroll
      for (int m=1;m<8;m++)
        if (wv[m] > Bv || (wv[m]==Bv && wi[m]<Bi)){ Bv=wv[m]; Bi=wi[m]; }
      sel[it]=Bi; sbi=Bi;
    }
    __syncthreads();
    int gw = sbi;
    if ((gw >> 5) == tid){          // owner removes winner, rescans locally
      int slot = gw & 31;
      #pragma unroll
      for (int i=0;i<32;i++) if (i==slot) v[i] = -3e38f;
      cm = -3e38f; ci = base;
      #pragma unroll
      for (int i=0;i<32;i++) if (v[i]>cm){ cm=v[i]; ci=base+i; }
    }
  }
  __syncthreads();
  if (tid < 64){                    // wave-0 bitonic sort ascending
    int x = sel[tid];
    #pragma unroll
    for (int size=2; size<=64; size<<=1){
      #pragma unroll
      for (int stride=size>>1; stride>0; stride>>=1){
        int ox = __shfl_xor(x, stride);
        bool up = ((tid & size) == 0);
        bool takeMin = (((tid & stride) == 0) == up);
        int mn = x < ox ? x : ox, mx = x < ox ? ox : x;
        x = takeMin ? mn : mx;
      }
    }
    idxo[b*64 + tid] = x;
  }
}

// ---------------- K4a: gather comb, layernorm, q/k/v projections --------------------
__global__ __launch_bounds__(256) void dsa_qkv(
    const float* __restrict__ a, const float* __restrict__ mq, const int* __restrict__ idx,
    const float* __restrict__ lnw, const float* __restrict__ lnb,
    const float* __restrict__ Wq, const float* __restrict__ bq,
    const float* __restrict__ Wk, const float* __restrict__ bk,
    const float* __restrict__ Wv, const float* __restrict__ bv,
    float* __restrict__ q, float* __restrict__ k, float* __restrict__ v)
{
  int b = blockIdx.x, tid = threadIdx.x;
  __shared__ float comb[80][64];
  __shared__ float xln[80][64];
  int col = tid & 63, rr = tid >> 6;
  for (int s0 = 0; s0 < 80; s0 += 4){
    int s = s0 + rr;
    float val;
    if (s < 16) val = mq[s*64 + col];
    else        val = a[((size_t)b*NB + idx[b*64 + (s-16)])*64 + col];
    comb[s][col] = val;
  }
  __syncthreads();
  int w = tid >> 6, lane = tid & 63;
  for (int s = w; s < 80; s += 4){
    float x = comb[s][lane];
    float sm = x, sq = x*x;
    #pragma unroll
    for (int m=1;m<64;m<<=1){ sm += __shfl_xor(sm,m); sq += __shfl_xor(sq,m); }
    float mu = sm*(1.0f/64.0f);
    float var = sq*(1.0f/64.0f) - mu*mu;
    xln[s][lane] = (x-mu)*rsqrtf(var + 1e-5f)*lnw[lane] + lnb[lane];
  }
  __syncthreads();
  for (int e = tid; e < 3*80*64; e += 256){
    int which = e / 5120;
    int r2 = e - which*5120;
    int s = r2 >> 6, d = r2 & 63;
    const float* W  = which==0 ? Wq : (which==1 ? Wk : Wv);
    const float* bb = which==0 ? bq : (which==1 ? bk : bv);
    float acc = bb[d];
    for (int c=0;c<64;c++) acc += xln[s][c]*W[c*64+d];
    float* dst = which==0 ? q : (which==1 ? k : v);
    dst[(b*80 + s)*64 + d] = acc;
  }
}

// ---------------- K4b: attention per head, output proj, enh_sparse ------------------
__global__ __launch_bounds__(256) void dsa_attn(
    const float* __restrict__ q, const float* __restrict__ k, const float* __restrict__ v,
    const float* __restrict__ Wo, const float* __restrict__ bo,
    const float* __restrict__ a, const int* __restrict__ idx,
    float* __restrict__ enh)
{
  int b = blockIdx.x, tid = threadIdx.x;
  __shared__ float qh[80][16], kh[80][16], vh[80][16];
  __shared__ float att[80][80];
  __shared__ float o[80][64];
  for (int h=0; h<4; ++h){
    for (int e = tid; e < 80*16; e += 256){
      int s = e >> 4, d = e & 15;
      qh[s][d] = q[(b*80+s)*64 + h*16 + d];
      kh[s][d] = k[(b*80+s)*64 + h*16 + d];
      vh[s][d] = v[(b*80+s)*64 + h*16 + d];
    }
    __syncthreads();
    for (int e = tid; e < 6400; e += 256){
      int i = e/80, j = e - (e/80)*80;
      float sc = 0.f;
      #pragma unroll
      for (int d=0; d<16; ++d) sc += qh[i][d]*kh[j][d];
      att[i][j] = sc * 0.25f;
    }
    __syncthreads();
    if (tid < 80){
      float mx = -3e38f;
      for (int j=0;j<80;j++) mx = fmaxf(mx, att[tid][j]);
      float sm = 0.f;
      for (int j=0;j<80;j++){ float e = expf(att[tid][j]-mx); att[tid][j]=e; sm+=e; }
      float inv = 1.0f/sm;
      for (int j=0;j<80;j++) att[tid][j] *= inv;
    }
    __syncthreads();
    for (int e = tid; e < 1280; e += 256){
      int i = e >> 4, d = e & 15;
      float sc = 0.f;
      for (int j=0;j<80;j++) sc += att[i][j]*vh[j][d];
      o[i][h*16+d] = sc;
    }
    __syncthreads();
  }
  for (int e = tid; e < 64*64; e += 256){
    int s = 16 + (e >> 6), c = e & 63;
    float acc = bo[c];
    for (int d=0; d<64; ++d) acc += o[s][d]*Wo[d*64+c];
    float cmb = a[((size_t)b*NB + idx[b*64 + (s-16)])*64 + c];
    enh[(b*64 + (s-16))*64 + c] = cmb + acc;
  }
}

// ---------------- K5: out[b, idx[j], :] += gamma * (enh[j] @ Wu) --------------------
__global__ __launch_bounds__(256) void dsa_scatter(
    const float* __restrict__ enh, const float* __restrict__ Wu,
    const float* __restrict__ gam, const int* __restrict__ idx,
    float* __restrict__ out)
{
  int blk = blockIdx.x;
  int b = blk >> 6, j = blk & 63;
  int tid = threadIdx.x;
  __shared__ float er[64];
  if (tid < 64) er[tid] = enh[(b*64+j)*64 + tid];
  __syncthreads();
  int n = idx[b*64 + j];
  float gamma = gam[0];
  int c0 = tid*4;
  float ax=0.f, ay=0.f, az=0.f, aw=0.f;
  for (int d=0; d<64; ++d){
    float ev = er[d];
    float4 wr = *(const float4*)(Wu + d*CDIM + c0);
    ax += ev*wr.x; ay += ev*wr.y; az += ev*wr.z; aw += ev*wr.w;
  }
  float* op = out + ((size_t)b*NB + n)*CDIM + c0;
  float4 cu = *(float4*)op;
  cu.x += gamma*ax; cu.y += gamma*ay; cu.z += gamma*az; cu.w += gamma*aw;
  *(float4*)op = cu;
}

extern "C" void kernel_launch(void* const* d_in, const int* in_sizes, int n_in,
                              void* d_out, int out_size, void* d_ws, size_t ws_size,
                              hipStream_t stream) {
  const float* X    = (const float*)d_in[0];
  const float* tf   = (const float*)d_in[1];
  const float* Wd   = (const float*)d_in[2];
  const float* bd   = (const float*)d_in[3];
  const float* Wu   = (const float*)d_in[4];
  const float* bu   = (const float*)d_in[5];
  const float* mq   = (const float*)d_in[6];
  const float* Wq   = (const float*)d_in[7];
  const float* bq   = (const float*)d_in[8];
  const float* Wk   = (const float*)d_in[9];
  const float* bk   = (const float*)d_in[10];
  const float* Wv   = (const float*)d_in[11];
  const float* bv   = (const float*)d_in[12];
  const float* Wo   = (const float*)d_in[13];
  const float* bo   = (const float*)d_in[14];
  const float* lnw  = (const float*)d_in[15];
  const float* lnb  = (const float*)d_in[16];
  const float* gam  = (const float*)d_in[17];
  float* out = (float*)d_out;

  float* ws_a               = (float*)d_ws;                 // 65536*64
  unsigned short* ws_wt     = (unsigned short*)(ws_a + (size_t)NROWS*DDIM);
  float* ws_scores          = (float*)(ws_wt + 64*CDIM);    // 65536
  float* ws_seln            = ws_scores + NROWS;            // 256
  int*   ws_idx             = (int*)(ws_seln + 256);        // 256
  float* ws_q               = (float*)(ws_idx + 256);       // 4*80*64
  float* ws_k               = ws_q + 4*80*64;
  float* ws_v               = ws_k + 4*80*64;
  float* ws_enh             = ws_v + 4*80*64;               // 4*64*64

  dsa_prep   <<<257, 256, 0, stream>>>(Wd, tf, ws_wt, ws_seln);
  dsa_main   <<<1024, 256, 0, stream>>>(X, ws_wt, bd, bu, gam, ws_seln,
                                        out, ws_a, ws_scores);
  dsa_topk   <<<4, 512, 0, stream>>>(ws_scores, ws_idx);
  dsa_qkv    <<<4, 256, 0, stream>>>(ws_a, mq, ws_idx, lnw, lnb,
                                     Wq, bq, Wk, bk, Wv, bv, ws_q, ws_k, ws_v);
  dsa_attn   <<<4, 256, 0, stream>>>(ws_q, ws_k, ws_v, Wo, bo, ws_a, ws_idx, ws_enh);
  dsa_scatter<<<256, 256, 0, stream>>>(ws_enh, Wu, gam, ws_idx, out);
}

// Round 2
// 379.130 us; speedup vs baseline: 1.2902x; 1.2902x over previous
//
#include <hip/hip_runtime.h>
#include <hip/hip_bf16.h>
#include <math.h>

typedef __bf16 bf16x8 __attribute__((ext_vector_type(8)));
typedef float  f32x4  __attribute__((ext_vector_type(4)));

#define CDIM 1024
#define DDIM 64
#define NB   16384
#define NROWS 65536

// float -> bf16 bits, round-to-nearest-even (finite inputs)
__device__ __forceinline__ unsigned short f2bf(float x){
  unsigned int u = __float_as_uint(x);
  unsigned int lsb = (u >> 16) & 1u;
  u += 0x7fffu + lsb;
  return (unsigned short)(u >> 16);
}

// ---------------- K0: transpose Wd -> bf16 Wt[n][k], and seln = l2norm(sel) ---------
__global__ void dsa_prep(const float* __restrict__ Wd, const float* __restrict__ tf,
                         unsigned short* __restrict__ Wt, float* __restrict__ seln){
  int bb = blockIdx.x, tid = threadIdx.x;
  if (bb < 256){
    int e = bb*256 + tid;            // 0..65535
    int kk = e >> 6, n = e & 63;     // Wd[kk][n]
    Wt[n*CDIM + kk] = f2bf(Wd[e]);
  } else {
    int w = tid >> 6, lane = tid & 63;   // wave w = batch w
    float x = tf[w*(20*512) + lane];     // text_features[b,0,lane]
    float sq = x*x;
    #pragma unroll
    for (int m=1; m<64; m<<=1) sq += __shfl_xor(sq, m);
    float nrm = fmaxf(sqrtf(sq), 1e-12f);
    seln[w*64 + lane] = x / nrm;
  }
}

// ---------------- K2: fused  out=X+g*bu  |  a=gelu(X@Wd+bd)  |  scores --------------
__global__ __launch_bounds__(256) void dsa_main(
    const float* __restrict__ X, const unsigned short* __restrict__ Wt,
    const float* __restrict__ bd, const float* __restrict__ bu,
    const float* __restrict__ gam, const float* __restrict__ seln,
    float* __restrict__ out, float* __restrict__ a_out, float* __restrict__ scores)
{
  __shared__ __align__(16) unsigned short As[2][4096];
  __shared__ __align__(16) unsigned short Bs[2][4096];
  const int tid  = threadIdx.x;
  const int lane = tid & 63;
  const int w    = tid >> 6;
  const int row0 = blockIdx.x * 64;
  const int batch = row0 >> 14;
  const float gamma = gam[0];

  const int kq   = tid & 15;   // A staging: k-quad (4 floats)
  const int rowb = tid >> 4;   // A staging: row base 0..15
  const int bn0  = tid >> 3;   // B staging: n 0..31 (+32)
  const int bko  = (tid & 7) * 8;

  float4 xr[4];
  uint4  br[2];

  auto loadStage = [&](int t){
    const int c0 = t*64 + kq*4;
    #pragma unroll
    for (int i=0;i<4;i++){
      int r = rowb + 16*i;
      xr[i] = *(const float4*)(X + (size_t)(row0+r)*CDIM + c0);
    }
    #pragma unroll
    for (int i=0;i<2;i++){
      int n = bn0 + 32*i;
      br[i] = *(const uint4*)(Wt + n*CDIM + t*64 + bko);
    }
  };
  auto writeStage = [&](int buf, int t){
    const int c0 = t*64 + kq*4;
    float4 bu4 = *(const float4*)(bu + c0);
    #pragma unroll
    for (int i=0;i<4;i++){
      int r = rowb + 16*i;
      float4 x = xr[i];
      float4 o4;
      o4.x = x.x + gamma*bu4.x; o4.y = x.y + gamma*bu4.y;
      o4.z = x.z + gamma*bu4.z; o4.w = x.w + gamma*bu4.w;
      *(float4*)(out + (size_t)(row0+r)*CDIM + c0) = o4;   // fused identity copy
      ushort4 u4;
      u4.x = f2bf(x.x); u4.y = f2bf(x.y); u4.z = f2bf(x.z); u4.w = f2bf(x.w);
      int off = (r*128 + kq*8) ^ ((r & 7) << 4);           // XOR swizzle (T2)
      *(ushort4*)((char*)(&As[buf][0]) + off) = u4;
    }
    #pragma unroll
    for (int i=0;i<2;i++){
      int n = bn0 + 32*i;
      int off = (n*128 + bko*2) ^ ((n & 7) << 4);
      *(uint4*)((char*)(&Bs[buf][0]) + off) = br[i];
    }
  };

  loadStage(0);
  writeStage(0, 0);
  __syncthreads();

  f32x4 acc[4] = {};
  int cur = 0;
  for (int t = 0; t < 16; ++t){
    if (t < 15) loadStage(t+1);
    const int arow = 16*w + (lane & 15);
    #pragma unroll
    for (int s=0;s<2;s++){
      int aoff = (arow*128 + s*64 + (lane>>4)*16) ^ ((arow & 7) << 4);
      bf16x8 av = *(const bf16x8*)((const char*)(&As[cur][0]) + aoff);
      #pragma unroll
      for (int j=0;j<4;j++){
        int bn = 16*j + (lane & 15);
        int boff = (bn*128 + s*64 + (lane>>4)*16) ^ ((bn & 7) << 4);
        bf16x8 bv = *(const bf16x8*)((const char*)(&Bs[cur][0]) + boff);
        acc[j] = __builtin_amdgcn_mfma_f32_16x16x32_bf16(av, bv, acc[j], 0,0,0);
      }
    }
    if (t < 15){ writeStage(cur^1, t+1); cur ^= 1; }
    __syncthreads();
  }

  // Epilogue: +bd, exact gelu, write a, fused l2norm-dot scores
  const float* selb = seln + batch*64;
  float ss[4] = {0,0,0,0}, dt[4] = {0,0,0,0};
  float gv[4][4];
  #pragma unroll
  for (int j=0;j<4;j++){
    int col = 16*j + (lane & 15);
    float bdc = bd[col];
    float sc  = selb[col];
    #pragma unroll
    for (int r=0;r<4;r++){
      float y = acc[j][r] + bdc;
      float g = 0.5f * y * (1.0f + erff(y * 0.70710678118654752f));
      gv[j][r] = g;
      ss[r] += g*g;
      dt[r] += g*sc;
    }
  }
  #pragma unroll
  for (int r=0;r<4;r++){
    int row = row0 + 16*w + 4*(lane>>4) + r;
    #pragma unroll
    for (int j=0;j<4;j++){
      int col = 16*j + (lane & 15);
      a_out[(size_t)row*DDIM + col] = gv[j][r];
    }
  }
  #pragma unroll
  for (int m=1;m<16;m<<=1){
    #pragma unroll
    for (int r=0;r<4;r++){
      ss[r] += __shfl_xor(ss[r], m);
      dt[r] += __shfl_xor(dt[r], m);
    }
  }
  if ((lane & 15) == 0){
    #pragma unroll
    for (int r=0;r<4;r++){
      int row = row0 + 16*w + 4*(lane>>4) + r;
      scores[row] = dt[r] / fmaxf(sqrtf(ss[r]), 1e-12f);
    }
  }
}

// ---------------- K3: per-batch top-64 (tournament) + ascending index sort ----------
__global__ __launch_bounds__(512) void dsa_topk(const float* __restrict__ scores,
                                                int* __restrict__ idxo){
  int b = blockIdx.x, tid = threadIdx.x;
  const float* s = scores + b*NB;
  float v[32];
  const int base = tid*32;
  #pragma unroll
  for (int i=0;i<32;i+=4){
    float4 f = *(const float4*)(s + base + i);
    v[i]=f.x; v[i+1]=f.y; v[i+2]=f.z; v[i+3]=f.w;
  }
  float cm = -3e38f; int ci = base;
  #pragma unroll
  for (int i=0;i<32;i++) if (v[i] > cm){ cm=v[i]; ci=base+i; }

  __shared__ float wv[8];
  __shared__ int   wi[8];
  __shared__ int   sbi;
  __shared__ int   sel[64];
  int lane = tid & 63, w = tid >> 6;

  for (int it=0; it<64; ++it){
    float bv = cm; int bi = ci;
    #pragma unroll
    for (int m=1;m<64;m<<=1){
      float ov = __shfl_xor(bv, m);
      int   oi = __shfl_xor(bi, m);
      if (ov > bv || (ov == bv && oi < bi)){ bv=ov; bi=oi; }
    }
    if (lane==0){ wv[w]=bv; wi[w]=bi; }
    __syncthreads();
    if (tid==0){
      float Bv = wv[0]; int Bi = wi[0];
      #pragma unroll
      for (int m=1;m<8;m++)
        if (wv[m] > Bv || (wv[m]==Bv && wi[m]<Bi)){ Bv=wv[m]; Bi=wi[m]; }
      sel[it]=Bi; sbi=Bi;
    }
    __syncthreads();
    int gw = sbi;
    if ((gw >> 5) == tid){          // owner removes winner, rescans locally
      int slot = gw & 31;
      #pragma unroll
      for (int i=0;i<32;i++) if (i==slot) v[i] = -3e38f;
      cm = -3e38f; ci = base;
      #pragma unroll
      for (int i=0;i<32;i++) if (v[i]>cm){ cm=v[i]; ci=base+i; }
    }
  }
  __syncthreads();
  if (tid < 64){                    // wave-0 bitonic sort ascending
    int x = sel[tid];
    #pragma unroll
    for (int size=2; size<=64; size<<=1){
      #pragma unroll
      for (int stride=size>>1; stride>0; stride>>=1){
        int ox = __shfl_xor(x, stride);
        bool up = ((tid & size) == 0);
        bool takeMin = (((tid & stride) == 0) == up);
        int mn = x < ox ? x : ox, mx = x < ox ? ox : x;
        x = takeMin ? mn : mx;
      }
    }
    idxo[b*64 + tid] = x;
  }
}

// ---------------- K4: fused per-batch tail: gather+LN+QKV+attention+Wo+enh ----------
__global__ __launch_bounds__(256) void dsa_tail(
    const float* __restrict__ a, const float* __restrict__ mq, const int* __restrict__ idx,
    const float* __restrict__ lnw, const float* __restrict__ lnb,
    const float* __restrict__ Wq, const float* __restrict__ bq,
    const float* __restrict__ Wk, const float* __restrict__ bk,
    const float* __restrict__ Wv, const float* __restrict__ bv,
    const float* __restrict__ Wo, const float* __restrict__ bo,
    float* __restrict__ enh)
{
  __shared__ float xln[80][64];   // layernormed comb
  __shared__ float q[80][64];
  __shared__ float v[80][64];
  __shared__ float kT[64][81];    // K transposed, padded (bank-safe)
  __shared__ float att[80][80];
  __shared__ float o[80][64];
  __shared__ float WoS[64][64];

  const int b = blockIdx.x, tid = threadIdx.x;
  const int w = tid >> 6, lane = tid & 63;

  // ---- P0: gather comb rows + layernorm (one wave per row, lane=col) ----
  {
    float lw = lnw[lane], lb = lnb[lane];
    for (int s = w; s < 80; s += 4){
      float val;
      if (s < 16) val = mq[s*64 + lane];
      else        val = a[((size_t)b*NB + idx[b*64 + (s-16)])*64 + lane];
      float sm = val, sq = val*val;
      #pragma unroll
      for (int m=1;m<64;m<<=1){ sm += __shfl_xor(sm,m); sq += __shfl_xor(sq,m); }
      float mu  = sm * (1.0f/64.0f);
      float var = sq * (1.0f/64.0f) - mu*mu;
      xln[s][lane] = (val - mu) * rsqrtf(var + 1e-5f) * lw + lb;
    }
  }
  __syncthreads();

  // ---- P1: QKV projections. W column in registers per lane. ----
  #pragma unroll 1
  for (int m = 0; m < 3; ++m){
    const float* Wm = (m==0) ? Wq : (m==1) ? Wk : Wv;
    const float* bm = (m==0) ? bq : (m==1) ? bk : bv;
    float wreg[64];
    #pragma unroll
    for (int c=0;c<64;c++) wreg[c] = Wm[c*64 + lane];   // coalesced, L2-hot
    float bias = bm[lane];
    #pragma unroll 1
    for (int s = w; s < 80; s += 4){
      float acc = bias;
      #pragma unroll
      for (int c4=0;c4<16;c4++){
        float4 x4 = *(const float4*)&xln[s][c4*4];      // LDS broadcast
        acc += x4.x*wreg[c4*4+0] + x4.y*wreg[c4*4+1]
             + x4.z*wreg[c4*4+2] + x4.w*wreg[c4*4+3];
      }
      if (m==0)      q[s][lane]  = acc;
      else if (m==1) kT[lane][s] = acc;
      else           v[s][lane]  = acc;
    }
  }
  __syncthreads();

  // ---- P2: attention, head by head ----
  for (int h = 0; h < 4; ++h){
    const int h16 = h*16;
    // scores: att[i][j] = (q[i]·k[j]) / 4
    for (int e = tid; e < 6400; e += 256){
      int i = e / 80, j = e - i*80;
      const float* qr = &q[i][h16];
      float acc = 0.f;
      #pragma unroll
      for (int d4=0; d4<4; d4++){
        float4 q4 = *(const float4*)(qr + d4*4);
        acc += q4.x*kT[h16+d4*4+0][j] + q4.y*kT[h16+d4*4+1][j]
             + q4.z*kT[h16+d4*4+2][j] + q4.w*kT[h16+d4*4+3][j];
      }
      att[i][j] = acc * 0.25f;
    }
    __syncthreads();
    // softmax per row (wave-parallel: lane covers j and j+64)
    for (int i = w; i < 80; i += 4){
      float v0 = att[i][lane];
      float v1 = (lane < 16) ? att[i][64+lane] : -3e38f;
      float mx = fmaxf(v0, v1);
      #pragma unroll
      for (int m=1;m<64;m<<=1) mx = fmaxf(mx, __shfl_xor(mx,m));
      float e0 = expf(v0 - mx);
      float e1 = (lane < 16) ? expf(v1 - mx) : 0.f;
      float sm = e0 + e1;
      #pragma unroll
      for (int m=1;m<64;m<<=1) sm += __shfl_xor(sm,m);
      float inv = 1.0f / sm;
      att[i][lane] = e0 * inv;
      if (lane < 16) att[i][64+lane] = e1 * inv;
    }
    __syncthreads();
    // PV: o[i][h16+dd] = sum_j att[i][j] * v[j][h16+dd]
    for (int e = tid; e < 1280; e += 256){
      int i = e >> 4, dd = e & 15;
      float acc = 0.f;
      #pragma unroll
      for (int j4=0; j4<20; j4++){
        float4 p4 = *(const float4*)&att[i][j4*4];
        acc += p4.x*v[j4*4+0][h16+dd] + p4.y*v[j4*4+1][h16+dd]
             + p4.z*v[j4*4+2][h16+dd] + p4.w*v[j4*4+3][h16+dd];
      }
      o[i][h16+dd] = acc;
    }
    __syncthreads();
  }

  // ---- P3: load Wo, enh = comb_sparse + o @ Wo + bo ----
  for (int e = tid; e < 4096; e += 256) WoS[e>>6][e&63] = Wo[e];
  __syncthreads();
  for (int e = tid; e < 4096; e += 256){
    int s16 = e >> 6, cc = e & 63;
    int s = 16 + s16;
    float acc = bo[cc];
    #pragma unroll
    for (int d4=0; d4<16; d4++){
      float4 o4 = *(const float4*)&o[s][d4*4];          // LDS broadcast
      acc += o4.x*WoS[d4*4+0][cc] + o4.y*WoS[d4*4+1][cc]
           + o4.z*WoS[d4*4+2][cc] + o4.w*WoS[d4*4+3][cc];
    }
    int n = idx[b*64 + s16];
    float cmb = a[((size_t)b*NB + n)*64 + cc];
    enh[(b*64 + s16)*64 + cc] = cmb + acc;
  }
}

// ---------------- K5: out[b, idx[j], :] += gamma * (enh[j] @ Wu) --------------------
__global__ __launch_bounds__(256) void dsa_scatter(
    const float* __restrict__ enh, const float* __restrict__ Wu,
    const float* __restrict__ gam, const int* __restrict__ idx,
    float* __restrict__ out)
{
  int blk = blockIdx.x;
  int b = blk >> 6, j = blk & 63;
  int tid = threadIdx.x;
  __shared__ float er[64];
  if (tid < 64) er[tid] = enh[(b*64+j)*64 + tid];
  __syncthreads();
  int n = idx[b*64 + j];
  float gamma = gam[0];
  int c0 = tid*4;
  float ax=0.f, ay=0.f, az=0.f, aw=0.f;
  for (int d=0; d<64; ++d){
    float ev = er[d];
    float4 wr = *(const float4*)(Wu + d*CDIM + c0);
    ax += ev*wr.x; ay += ev*wr.y; az += ev*wr.z; aw += ev*wr.w;
  }
  float* op = out + ((size_t)b*NB + n)*CDIM + c0;
  float4 cu = *(float4*)op;
  cu.x += gamma*ax; cu.y += gamma*ay; cu.z += gamma*az; cu.w += gamma*aw;
  *(float4*)op = cu;
}

extern "C" void kernel_launch(void* const* d_in, const int* in_sizes, int n_in,
                              void* d_out, int out_size, void* d_ws, size_t ws_size,
                              hipStream_t stream) {
  const float* X    = (const float*)d_in[0];
  const float* tf   = (const float*)d_in[1];
  const float* Wd   = (const float*)d_in[2];
  const float* bd   = (const float*)d_in[3];
  const float* Wu   = (const float*)d_in[4];
  const float* bu   = (const float*)d_in[5];
  const float* mq   = (const float*)d_in[6];
  const float* Wq   = (const float*)d_in[7];
  const float* bq   = (const float*)d_in[8];
  const float* Wk   = (const float*)d_in[9];
  const float* bk   = (const float*)d_in[10];
  const float* Wv   = (const float*)d_in[11];
  const float* bv   = (const float*)d_in[12];
  const float* Wo   = (const float*)d_in[13];
  const float* bo   = (const float*)d_in[14];
  const float* lnw  = (const float*)d_in[15];
  const float* lnb  = (const float*)d_in[16];
  const float* gam  = (const float*)d_in[17];
  float* out = (float*)d_out;

  float* ws_a               = (float*)d_ws;                 // 65536*64
  unsigned short* ws_wt     = (unsigned short*)(ws_a + (size_t)NROWS*DDIM);
  float* ws_scores          = (float*)(ws_wt + 64*CDIM);    // 65536
  float* ws_seln            = ws_scores + NROWS;            // 256
  int*   ws_idx             = (int*)(ws_seln + 256);        // 256
  float* ws_enh             = (float*)(ws_idx + 256);       // 4*64*64

  dsa_prep   <<<257, 256, 0, stream>>>(Wd, tf, ws_wt, ws_seln);
  dsa_main   <<<1024, 256, 0, stream>>>(X, ws_wt, bd, bu, gam, ws_seln,
                                        out, ws_a, ws_scores);
  dsa_topk   <<<4, 512, 0, stream>>>(ws_scores, ws_idx);
  dsa_tail   <<<4, 256, 0, stream>>>(ws_a, mq, ws_idx, lnw, lnb,
                                     Wq, bq, Wk, bk, Wv, bv, Wo, bo, ws_enh);
  dsa_scatter<<<256, 256, 0, stream>>>(ws_enh, Wu, gam, ws_idx, out);
}

// Round 3
// 229.235 us; speedup vs baseline: 2.1338x; 1.6539x over previous
//
#include <hip/hip_runtime.h>
#include <hip/hip_bf16.h>
#include <math.h>

typedef __bf16 bf16x8 __attribute__((ext_vector_type(8)));
typedef unsigned short u16x8 __attribute__((ext_vector_type(8)));
typedef float f32x4 __attribute__((ext_vector_type(4)));

#define CDIM 1024
#define DDIM 64
#define NB   16384
#define NROWS 65536

// float -> bf16 bits, round-to-nearest-even (finite inputs)
__device__ __forceinline__ unsigned short f2bf(float x){
  unsigned int u = __float_as_uint(x);
  unsigned int lsb = (u >> 16) & 1u;
  u += 0x7fffu + lsb;
  return (unsigned short)(u >> 16);
}

// ---------------- K0: Wd -> fragment-major bf16 Wf, and seln = l2norm(sel) ----------
// Wf element index: ((t*4 + j)*64 + lane)*8 + e  holds  Wd[k][n],
//   n = j*16 + (lane&15),  k = t*32 + (lane>>4)*8 + e      (t = 0..31, j = 0..3)
__global__ __launch_bounds__(256) void dsa_prep(
    const float* __restrict__ Wd, const float* __restrict__ tf,
    unsigned short* __restrict__ Wf, float* __restrict__ seln){
  int bb = blockIdx.x, tid = threadIdx.x;
  if (bb < 32){
    int g = bb*256 + tid;            // 0..8191
    int lane = g & 63, tj = g >> 6;  // tj = t*4+j
    int n  = ((tj & 3) << 4) + (lane & 15);
    int k0 = ((tj >> 2) << 5) + ((lane >> 4) << 3);
    u16x8 uv;
    #pragma unroll
    for (int e=0;e<8;e++) uv[e] = f2bf(Wd[(k0+e)*DDIM + n]);
    *(u16x8*)(Wf + (size_t)g*8) = uv;
  } else {
    int w = tid >> 6, lane = tid & 63;   // wave w = batch w
    float x = tf[w*(20*512) + lane];     // text_features[b,0,lane]
    float sq = x*x;
    #pragma unroll
    for (int m=1; m<64; m<<=1) sq += __shfl_xor(sq, m);
    seln[w*64 + lane] = x / fmaxf(sqrtf(sq), 1e-12f);
  }
}

// ---------------- K1: barrier-free fused  out=X+g*bu | a=gelu(X@Wd+bd) | scores -----
__global__ __launch_bounds__(256) void dsa_main(
    const float* __restrict__ X, const unsigned short* __restrict__ Wf,
    const float* __restrict__ bd, const float* __restrict__ bu,
    const float* __restrict__ gam, const float* __restrict__ seln,
    float* __restrict__ out, float* __restrict__ a_out, float* __restrict__ scores)
{
  const int tid  = threadIdx.x;
  const int lane = tid & 63, w = tid >> 6;
  const int row0 = blockIdx.x*64 + w*16;      // this wave's 16 rows
  const int batch = blockIdx.x >> 8;          // 256 blocks per batch
  const float gamma = gam[0];
  const int lr = lane & 15, lq = lane >> 4;

  const size_t rowoff = (size_t)(row0 + lr)*CDIM + lq*8;
  const float* xp = X   + rowoff;
  float*       op = out + rowoff;
  const float* bup = bu + lq*8;
  const bf16x8* wf8 = (const bf16x8*)Wf;

  f32x4 acc[4] = {};

  #pragma unroll 2
  for (int t = 0; t < 32; ++t){
    f32x4 xa = *(const f32x4*)(xp + t*32);
    f32x4 xb = *(const f32x4*)(xp + t*32 + 4);
    bf16x8 bv0 = wf8[(t*4+0)*64 + lane];
    bf16x8 bv1 = wf8[(t*4+1)*64 + lane];
    bf16x8 bv2 = wf8[(t*4+2)*64 + lane];
    bf16x8 bv3 = wf8[(t*4+3)*64 + lane];
    f32x4 ba = *(const f32x4*)(bup + t*32);
    f32x4 bb = *(const f32x4*)(bup + t*32 + 4);
    // fused identity copy (nontemporal: out is written once, keep LLC for X)
    f32x4 oa = xa + gamma*ba;
    f32x4 ob = xb + gamma*bb;
    __builtin_nontemporal_store(oa, (f32x4*)(op + t*32));
    __builtin_nontemporal_store(ob, (f32x4*)(op + t*32 + 4));
    union { u16x8 u; bf16x8 b; } cv;
    cv.u[0]=f2bf(xa[0]); cv.u[1]=f2bf(xa[1]); cv.u[2]=f2bf(xa[2]); cv.u[3]=f2bf(xa[3]);
    cv.u[4]=f2bf(xb[0]); cv.u[5]=f2bf(xb[1]); cv.u[6]=f2bf(xb[2]); cv.u[7]=f2bf(xb[3]);
    acc[0] = __builtin_amdgcn_mfma_f32_16x16x32_bf16(cv.b, bv0, acc[0], 0,0,0);
    acc[1] = __builtin_amdgcn_mfma_f32_16x16x32_bf16(cv.b, bv1, acc[1], 0,0,0);
    acc[2] = __builtin_amdgcn_mfma_f32_16x16x32_bf16(cv.b, bv2, acc[2], 0,0,0);
    acc[3] = __builtin_amdgcn_mfma_f32_16x16x32_bf16(cv.b, bv3, acc[3], 0,0,0);
  }

  // Epilogue: +bd, exact gelu, write a, fused l2norm-dot scores
  const float* selb = seln + batch*64;
  float ss[4] = {0,0,0,0}, dt[4] = {0,0,0,0};
  float gv[4][4];
  #pragma unroll
  for (int j=0;j<4;j++){
    int col = 16*j + lr;
    float bdc = bd[col];
    float sc  = selb[col];
    #pragma unroll
    for (int r=0;r<4;r++){
      float y = acc[j][r] + bdc;
      float g = 0.5f * y * (1.0f + erff(y * 0.70710678118654752f));
      gv[j][r] = g;
      ss[r] += g*g;
      dt[r] += g*sc;
    }
  }
  #pragma unroll
  for (int r=0;r<4;r++){
    int row = row0 + 4*lq + r;
    #pragma unroll
    for (int j=0;j<4;j++)
      a_out[(size_t)row*DDIM + 16*j + lr] = gv[j][r];
  }
  #pragma unroll
  for (int m=1;m<16;m<<=1){
    #pragma unroll
    for (int r=0;r<4;r++){
      ss[r] += __shfl_xor(ss[r], m);
      dt[r] += __shfl_xor(dt[r], m);
    }
  }
  if (lr == 0){
    #pragma unroll
    for (int r=0;r<4;r++)
      scores[row0 + 4*lq + r] = dt[r] / fmaxf(sqrtf(ss[r]), 1e-12f);
  }
}

// ---------------- K2: per-batch exact top-64 via 8-bit radix select -----------------
__global__ __launch_bounds__(1024) void dsa_topk(const float* __restrict__ scores,
                                                 int* __restrict__ idxo){
  const int b = blockIdx.x, tid = threadIdx.x;
  const float* s = scores + b*NB;
  const int base = tid*16;
  unsigned key[16];
  #pragma unroll
  for (int i=0;i<16;i+=4){
    f32x4 f = *(const f32x4*)(s + base + i);
    #pragma unroll
    for (int c=0;c<4;c++){
      unsigned u = __float_as_uint(f[c]);
      key[i+c] = (u & 0x80000000u) ? ~u : (u | 0x80000000u);  // ascending uint order
    }
  }

  __shared__ unsigned bins[256];
  __shared__ unsigned sh_pref, sh_R;
  __shared__ int selIdx[64];
  __shared__ int eqIdx[256];
  __shared__ unsigned selCnt, eqCnt;

  unsigned prefix = 0, R = 64;
  for (int pass=0; pass<4; ++pass){
    const int shift = 24 - pass*8;
    if (tid < 256) bins[tid] = 0;
    __syncthreads();
    #pragma unroll
    for (int i=0;i<16;i++){
      unsigned k = key[i];
      bool ok;
      if (pass == 0) ok = true;
      else           ok = ((k >> (shift+8)) == prefix);
      if (ok) atomicAdd(&bins[(k >> shift) & 255u], 1u);
    }
    __syncthreads();
    if (tid < 64){
      unsigned c0 = bins[tid*4+0], c1 = bins[tid*4+1];
      unsigned c2 = bins[tid*4+2], c3 = bins[tid*4+3];
      unsigned gs = c0+c1+c2+c3;
      unsigned suf = gs;                       // inclusive suffix sum over 64 groups
      #pragma unroll
      for (int m=1;m<64;m<<=1){
        unsigned o = __shfl_down(suf, m);
        if (tid + m < 64) suf += o;
      }
      unsigned above = suf - gs;               // strictly-above-this-group count
      if (above < R && R <= suf){              // exactly one lane
        unsigned a3 = above;
        unsigned a2 = a3 + c3;
        unsigned a1 = a2 + c2;
        unsigned a0 = a1 + c1;
        unsigned bb, ab;
        if      (R <= a3 + c3){ bb = 3; ab = a3; }
        else if (R <= a2 + c2){ bb = 2; ab = a2; }
        else if (R <= a1 + c1){ bb = 1; ab = a1; }
        else                  { bb = 0; ab = a0; }
        sh_pref = (prefix << 8) | (tid*4 + bb);
        sh_R = R - ab;
      }
    }
    __syncthreads();
    prefix = sh_pref; R = sh_R;
    __syncthreads();
  }
  // prefix == exact key of 64th-largest; need R of the equal keys (smallest indices)
  if (tid == 0){ selCnt = 0; eqCnt = 0; }
  __syncthreads();
  #pragma unroll
  for (int i=0;i<16;i++){
    unsigned k = key[i];
    if (k > prefix){
      selIdx[atomicAdd(&selCnt, 1u)] = base + i;
    } else if (k == prefix){
      unsigned p = atomicAdd(&eqCnt, 1u);
      if (p < 256) eqIdx[p] = base + i;
    }
  }
  __syncthreads();
  if (tid == 0){
    unsigned n = eqCnt < 256u ? eqCnt : 256u;
    unsigned have = selCnt;
    for (unsigned r2 = 0; r2 < R; ++r2){
      int best = 0x7fffffff, bi = -1;
      for (unsigned e=0; e<n; e++)
        if (eqIdx[e] < best){ best = eqIdx[e]; bi = (int)e; }
      selIdx[have + r2] = best;
      eqIdx[bi] = 0x7fffffff;
    }
  }
  __syncthreads();
  if (tid < 64){                    // wave-0 bitonic sort ascending
    int x = selIdx[tid];
    #pragma unroll
    for (int size=2; size<=64; size<<=1){
      #pragma unroll
      for (int stride=size>>1; stride>0; stride>>=1){
        int ox = __shfl_xor(x, stride);
        bool up = ((tid & size) == 0);
        bool takeMin = (((tid & stride) == 0) == up);
        int mn = x < ox ? x : ox, mx = x < ox ? ox : x;
        x = takeMin ? mn : mx;
      }
    }
    idxo[b*64 + tid] = x;
  }
}

// ---------------- K3: fused per-batch tail: gather+LN+QKV+attention+Wo+enh ----------
__global__ __launch_bounds__(512) void dsa_tail(
    const float* __restrict__ a, const float* __restrict__ mq, const int* __restrict__ idx,
    const float* __restrict__ lnw, const float* __restrict__ lnb,
    const float* __restrict__ Wq, const float* __restrict__ bq,
    const float* __restrict__ Wk, const float* __restrict__ bk,
    const float* __restrict__ Wv, const float* __restrict__ bv,
    const float* __restrict__ Wo, const float* __restrict__ bo,
    float* __restrict__ enh)
{
  __shared__ float xln[80][64];
  __shared__ float qS[80][64];
  __shared__ float vS[80][68];     // padded: PV 4-group read -> 2-way (free)
  __shared__ float kT[64][81];     // K transposed, padded
  __shared__ float oS[80][64];
  __shared__ float WoS[64][64];
  __shared__ float rowbuf[8][84];  // per-wave prob row
  __shared__ int   sidx[64];

  const int b = blockIdx.x, tid = threadIdx.x;
  const int w = tid >> 6, lane = tid & 63;

  if (tid < 64) sidx[tid] = idx[b*64 + tid];
  for (int e = tid; e < 4096; e += 512) WoS[e>>6][e&63] = Wo[e];  // overlap with P0
  __syncthreads();

  // ---- P0: gather comb rows + layernorm (10 rows per wave, loads prefetched) ----
  {
    float lw = lnw[lane], lb = lnb[lane];
    float vals[10];
    #pragma unroll
    for (int i=0;i<10;i++){
      int s = w + 8*i;
      vals[i] = (s < 16) ? mq[s*64 + lane]
                         : a[((size_t)b*NB + sidx[s-16])*64 + lane];
    }
    #pragma unroll
    for (int i=0;i<10;i++){
      int s = w + 8*i;
      float val = vals[i];
      float sm = val, sq = val*val;
      #pragma unroll
      for (int m=1;m<64;m<<=1){ sm += __shfl_xor(sm,m); sq += __shfl_xor(sq,m); }
      float mu  = sm * (1.0f/64.0f);
      float var = sq * (1.0f/64.0f) - mu*mu;
      xln[s][lane] = (val - mu) * rsqrtf(var + 1e-5f) * lw + lb;
    }
  }
  __syncthreads();

  // ---- P1: QKV projections. W column in registers per lane. ----
  #pragma unroll 1
  for (int m = 0; m < 3; ++m){
    const float* Wm = (m==0) ? Wq : (m==1) ? Wk : Wv;
    const float* bm = (m==0) ? bq : (m==1) ? bk : bv;
    float wreg[64];
    #pragma unroll
    for (int c=0;c<64;c++) wreg[c] = Wm[c*64 + lane];
    float bias = bm[lane];
    #pragma unroll 1
    for (int s = w; s < 80; s += 8){
      float accv = bias;
      #pragma unroll
      for (int c4=0;c4<16;c4++){
        f32x4 x4 = *(const f32x4*)&xln[s][c4*4];
        accv += x4[0]*wreg[c4*4+0] + x4[1]*wreg[c4*4+1]
              + x4[2]*wreg[c4*4+2] + x4[3]*wreg[c4*4+3];
      }
      if (m==0)      qS[s][lane]  = accv;
      else if (m==1) kT[lane][s]  = accv;
      else           vS[s][lane]  = accv;
    }
  }
  __syncthreads();

  // ---- P2: fused scores+softmax+PV. Wave pair per head; rows 16..79 only. ----
  {
    const int h = w >> 1, h16 = h*16;
    const int i0 = 16 + (w & 1)*32;
    const int jj = lane >> 4, dd = lane & 15;
    #pragma unroll 2
    for (int ii = 0; ii < 32; ++ii){
      int i = i0 + ii;
      float v0 = 0.f, v1 = 0.f;
      #pragma unroll
      for (int d=0; d<16; ++d){
        float qd = qS[i][h16+d];
        v0 = fmaf(qd, kT[h16+d][lane],    v0);
        v1 = fmaf(qd, kT[h16+d][64 + dd], v1);
      }
      v0 *= 0.25f; v1 *= 0.25f;
      float mx = fmaxf(v0, v1);
      #pragma unroll
      for (int m2=1;m2<64;m2<<=1) mx = fmaxf(mx, __shfl_xor(mx,m2));
      float e0 = expf(v0 - mx);
      float e1 = expf(v1 - mx);
      float sm = e0 + ((lane < 16) ? e1 : 0.f);
      #pragma unroll
      for (int m2=1;m2<64;m2<<=1) sm += __shfl_xor(sm,m2);
      float inv = 1.0f / sm;
      rowbuf[w][lane] = e0 * inv;
      if (lane < 16) rowbuf[w][64+dd] = e1 * inv;
      // PV partials: lane = (jj,dd); same-wave LDS ordering guarantees visibility
      float part = 0.f;
      #pragma unroll
      for (int tt=0; tt<20; ++tt){
        int j = jj*20 + tt;
        part = fmaf(rowbuf[w][j], vS[j][h16+dd], part);
      }
      part += __shfl_xor(part, 16);
      part += __shfl_xor(part, 32);
      if (lane < 16) oS[i][h16+dd] = part;
    }
  }
  __syncthreads();

  // ---- P3: enh = comb_sparse + o @ Wo + bo ----
  for (int e = tid; e < 4096; e += 512){
    int s16 = e >> 6, cc = e & 63;
    float accv = bo[cc];
    #pragma unroll
    for (int d4=0; d4<16; ++d4){
      f32x4 o4 = *(const f32x4*)&oS[16+s16][d4*4];
      accv += o4[0]*WoS[d4*4+0][cc] + o4[1]*WoS[d4*4+1][cc]
            + o4[2]*WoS[d4*4+2][cc] + o4[3]*WoS[d4*4+3][cc];
    }
    float cmb = a[((size_t)b*NB + sidx[s16])*64 + cc];
    enh[(b*64 + s16)*64 + cc] = cmb + accv;
  }
}

// ---------------- K4: out[b, idx[j], :] += gamma * (enh[j] @ Wu) --------------------
__global__ __launch_bounds__(256) void dsa_scatter(
    const float* __restrict__ enh, const float* __restrict__ Wu,
    const float* __restrict__ gam, const int* __restrict__ idx,
    float* __restrict__ out)
{
  int blk = blockIdx.x;
  int b = blk >> 6, j = blk & 63;
  int tid = threadIdx.x;
  __shared__ float er[64];
  if (tid < 64) er[tid] = enh[(b*64+j)*64 + tid];
  __syncthreads();
  int n = idx[b*64 + j];
  float gamma = gam[0];
  int c0 = tid*4;
  float ax=0.f, ay=0.f, az=0.f, aw=0.f;
  #pragma unroll 8
  for (int d=0; d<64; ++d){
    float ev = er[d];
    f32x4 wr = *(const f32x4*)(Wu + d*CDIM + c0);
    ax += ev*wr[0]; ay += ev*wr[1]; az += ev*wr[2]; aw += ev*wr[3];
  }
  float* op = out + ((size_t)b*NB + n)*CDIM + c0;
  f32x4 cu = *(f32x4*)op;
  cu[0] += gamma*ax; cu[1] += gamma*ay; cu[2] += gamma*az; cu[3] += gamma*aw;
  *(f32x4*)op = cu;
}

extern "C" void kernel_launch(void* const* d_in, const int* in_sizes, int n_in,
                              void* d_out, int out_size, void* d_ws, size_t ws_size,
                              hipStream_t stream) {
  const float* X    = (const float*)d_in[0];
  const float* tf   = (const float*)d_in[1];
  const float* Wd   = (const float*)d_in[2];
  const float* bd   = (const float*)d_in[3];
  const float* Wu   = (const float*)d_in[4];
  const float* bu   = (const float*)d_in[5];
  const float* mq   = (const float*)d_in[6];
  const float* Wq   = (const float*)d_in[7];
  const float* bq   = (const float*)d_in[8];
  const float* Wk   = (const float*)d_in[9];
  const float* bk   = (const float*)d_in[10];
  const float* Wv   = (const float*)d_in[11];
  const float* bv   = (const float*)d_in[12];
  const float* Wo   = (const float*)d_in[13];
  const float* bo   = (const float*)d_in[14];
  const float* lnw  = (const float*)d_in[15];
  const float* lnb  = (const float*)d_in[16];
  const float* gam  = (const float*)d_in[17];
  float* out = (float*)d_out;

  float* ws_a               = (float*)d_ws;                 // 65536*64
  unsigned short* ws_wf     = (unsigned short*)(ws_a + (size_t)NROWS*DDIM);
  float* ws_scores          = (float*)(ws_wf + 64*CDIM);    // 65536
  float* ws_seln            = ws_scores + NROWS;            // 256
  int*   ws_idx             = (int*)(ws_seln + 256);        // 256
  float* ws_enh             = (float*)(ws_idx + 256);       // 4*64*64

  dsa_prep   <<<33,   256, 0, stream>>>(Wd, tf, ws_wf, ws_seln);
  dsa_main   <<<1024, 256, 0, stream>>>(X, ws_wf, bd, bu, gam, ws_seln,
                                        out, ws_a, ws_scores);
  dsa_topk   <<<4,   1024, 0, stream>>>(ws_scores, ws_idx);
  dsa_tail   <<<4,    512, 0, stream>>>(ws_a, mq, ws_idx, lnw, lnb,
                                        Wq, bq, Wk, bk, Wv, bv, Wo, bo, ws_enh);
  dsa_scatter<<<256,  256, 0, stream>>>(ws_enh, Wu, gam, ws_idx, out);
}

// Round 4
// 211.727 us; speedup vs baseline: 2.3103x; 1.0827x over previous
//
#include <hip/hip_runtime.h>
#include <hip/hip_bf16.h>
#include <math.h>

typedef __bf16 bf16x8 __attribute__((ext_vector_type(8)));
typedef unsigned short u16x8 __attribute__((ext_vector_type(8)));
typedef float f32x4 __attribute__((ext_vector_type(4)));

#define CDIM 1024
#define DDIM 64
#define NB   16384
#define NROWS 65536

// float -> bf16 bits, round-to-nearest-even (finite inputs)
__device__ __forceinline__ unsigned short f2bf(float x){
  unsigned int u = __float_as_uint(x);
  unsigned int lsb = (u >> 16) & 1u;
  u += 0x7fffu + lsb;
  return (unsigned short)(u >> 16);
}

// ---------------- K0: Wd -> fragment-major bf16 Wf; seln = l2norm(sel); gbu --------
// Wf element index: ((t*4 + j)*64 + lane)*8 + e  holds  Wd[k][n],
//   n = j*16 + (lane&15),  k = t*32 + (lane>>4)*8 + e      (t = 0..31, j = 0..3)
__global__ __launch_bounds__(256) void dsa_prep(
    const float* __restrict__ Wd, const float* __restrict__ tf,
    const float* __restrict__ bu, const float* __restrict__ gam,
    unsigned short* __restrict__ Wf, float* __restrict__ seln,
    float* __restrict__ gbu){
  int bb = blockIdx.x, tid = threadIdx.x;
  if (bb < 32){
    int g = bb*256 + tid;            // 0..8191
    int lane = g & 63, tj = g >> 6;  // tj = t*4+j
    int n  = ((tj & 3) << 4) + (lane & 15);
    int k0 = ((tj >> 2) << 5) + ((lane >> 4) << 3);
    u16x8 uv;
    #pragma unroll
    for (int e=0;e<8;e++) uv[e] = f2bf(Wd[(k0+e)*DDIM + n]);
    *(u16x8*)(Wf + (size_t)g*8) = uv;
  } else {
    int w = tid >> 6, lane = tid & 63;   // wave w = batch w
    float x = tf[w*(20*512) + lane];     // text_features[b,0,lane]
    float sq = x*x;
    #pragma unroll
    for (int m=1; m<64; m<<=1) sq += __shfl_xor(sq, m);
    seln[w*64 + lane] = x / fmaxf(sqrtf(sq), 1e-12f);
    float g = gam[0];
    f32x4 b4 = *(const f32x4*)(bu + tid*4);
    *(f32x4*)(gbu + tid*4) = g*b4;
  }
}

// ---------------- K1: fused  out=X+gbu | a=gelu(X@Wd+bd) | scores -------------------
// B (Wf) staged in LDS in 8 double-buffered K-phases (reg-staged) so the vmcnt
// stream contains ONLY the X loads (prefetched one phase ahead).
__global__ __launch_bounds__(256) void dsa_main(
    const float* __restrict__ X, const unsigned short* __restrict__ Wf,
    const float* __restrict__ bd, const float* __restrict__ gbu,
    const float* __restrict__ seln,
    float* __restrict__ out, float* __restrict__ a_out, float* __restrict__ scores)
{
  __shared__ __align__(16) unsigned short Bs[2][8192];  // 2 x 16 KB (one K-phase each)
  __shared__ __align__(16) float gbS[1024];             // gamma*bu
  const int tid  = threadIdx.x;
  const int lane = tid & 63, w = tid >> 6;
  const int lr = lane & 15, lq = lane >> 4;
  const int row0 = blockIdx.x*64 + w*16;       // this wave's 16 rows
  const int batch = blockIdx.x >> 8;           // 256 blocks per batch

  const size_t rowoff = (size_t)(row0 + lr)*CDIM + lq*8;
  const float* xp = X   + rowoff;
  float*       op = out + rowoff;

  f32x4 xr0[4][2], xr1[4][2];   // A ring: current / next phase (4 steps each)
  uint4 st[4];                  // B staging registers (16 B x 4 = one phase / thread)
  f32x4 acc[4] = {};

#define LD_B(P) { \
    st[0] = *(const uint4*)(Wf + (P)*8192 + 0*2048 + tid*8); \
    st[1] = *(const uint4*)(Wf + (P)*8192 + 1*2048 + tid*8); \
    st[2] = *(const uint4*)(Wf + (P)*8192 + 2*2048 + tid*8); \
    st[3] = *(const uint4*)(Wf + (P)*8192 + 3*2048 + tid*8); }
#define ST_B(BUFI) { \
    *(uint4*)(&Bs[BUFI][0*2048 + tid*8]) = st[0]; \
    *(uint4*)(&Bs[BUFI][1*2048 + tid*8]) = st[1]; \
    *(uint4*)(&Bs[BUFI][2*2048 + tid*8]) = st[2]; \
    *(uint4*)(&Bs[BUFI][3*2048 + tid*8]) = st[3]; }
#define LD_A(R, P) { \
    R[0][0]=*(const f32x4*)(xp+(P)*128+  0); R[0][1]=*(const f32x4*)(xp+(P)*128+  4); \
    R[1][0]=*(const f32x4*)(xp+(P)*128+ 32); R[1][1]=*(const f32x4*)(xp+(P)*128+ 36); \
    R[2][0]=*(const f32x4*)(xp+(P)*128+ 64); R[2][1]=*(const f32x4*)(xp+(P)*128+ 68); \
    R[3][0]=*(const f32x4*)(xp+(P)*128+ 96); R[3][1]=*(const f32x4*)(xp+(P)*128+100); }
#define STEP(BUFI, TL, R, P) { \
    f32x4 xa = R[TL][0], xb = R[TL][1]; \
    f32x4 g0 = *(const f32x4*)(&gbS[(P)*128 + (TL)*32 + lq*8]); \
    f32x4 g1 = *(const f32x4*)(&gbS[(P)*128 + (TL)*32 + lq*8 + 4]); \
    *(f32x4*)(op + (P)*128 + (TL)*32)     = xa + g0; \
    *(f32x4*)(op + (P)*128 + (TL)*32 + 4) = xb + g1; \
    bf16x8 av; \
    av[0]=(__bf16)xa[0]; av[1]=(__bf16)xa[1]; av[2]=(__bf16)xa[2]; av[3]=(__bf16)xa[3]; \
    av[4]=(__bf16)xb[0]; av[5]=(__bf16)xb[1]; av[6]=(__bf16)xb[2]; av[7]=(__bf16)xb[3]; \
    bf16x8 b0 = *(const bf16x8*)(&Bs[BUFI][(TL)*2048 + 0*512 + lane*8]); \
    bf16x8 b1 = *(const bf16x8*)(&Bs[BUFI][(TL)*2048 + 1*512 + lane*8]); \
    bf16x8 b2 = *(const bf16x8*)(&Bs[BUFI][(TL)*2048 + 2*512 + lane*8]); \
    bf16x8 b3 = *(const bf16x8*)(&Bs[BUFI][(TL)*2048 + 3*512 + lane*8]); \
    acc[0] = __builtin_amdgcn_mfma_f32_16x16x32_bf16(av, b0, acc[0], 0,0,0); \
    acc[1] = __builtin_amdgcn_mfma_f32_16x16x32_bf16(av, b1, acc[1], 0,0,0); \
    acc[2] = __builtin_amdgcn_mfma_f32_16x16x32_bf16(av, b2, acc[2], 0,0,0); \
    acc[3] = __builtin_amdgcn_mfma_f32_16x16x32_bf16(av, b3, acc[3], 0,0,0); }
#define PHASE(K, RCUR, RNXT) { \
    LD_B((K)+1); LD_A(RNXT, (K)+1); \
    STEP((K)&1, 0, RCUR, K) STEP((K)&1, 1, RCUR, K) \
    STEP((K)&1, 2, RCUR, K) STEP((K)&1, 3, RCUR, K) \
    ST_B(((K)+1)&1); __syncthreads(); }

  // prologue: gbu -> LDS, stage phase 0
  { f32x4 t = *(const f32x4*)(gbu + tid*4); *(f32x4*)(&gbS[tid*4]) = t; }
  LD_B(0); LD_A(xr0, 0);
  ST_B(0);
  __syncthreads();

  PHASE(0, xr0, xr1)
  PHASE(1, xr1, xr0)
  PHASE(2, xr0, xr1)
  PHASE(3, xr1, xr0)
  PHASE(4, xr0, xr1)
  PHASE(5, xr1, xr0)
  PHASE(6, xr0, xr1)
  // phase 7: no prefetch
  STEP(1, 0, xr1, 7) STEP(1, 1, xr1, 7) STEP(1, 2, xr1, 7) STEP(1, 3, xr1, 7)

#undef LD_B
#undef ST_B
#undef LD_A
#undef STEP
#undef PHASE

  // Epilogue: +bd, exact gelu, write a, fused l2norm-dot scores
  const float* selb = seln + batch*64;
  float ss[4] = {0,0,0,0}, dt[4] = {0,0,0,0};
  float gv[4][4];
  #pragma unroll
  for (int j=0;j<4;j++){
    int col = 16*j + lr;
    float bdc = bd[col];
    float sc  = selb[col];
    #pragma unroll
    for (int r=0;r<4;r++){
      float y = acc[j][r] + bdc;
      float g = 0.5f * y * (1.0f + erff(y * 0.70710678118654752f));
      gv[j][r] = g;
      ss[r] += g*g;
      dt[r] += g*sc;
    }
  }
  #pragma unroll
  for (int r=0;r<4;r++){
    int row = row0 + 4*lq + r;
    #pragma unroll
    for (int j=0;j<4;j++)
      a_out[(size_t)row*DDIM + 16*j + lr] = gv[j][r];
  }
  #pragma unroll
  for (int m=1;m<16;m<<=1){
    #pragma unroll
    for (int r=0;r<4;r++){
      ss[r] += __shfl_xor(ss[r], m);
      dt[r] += __shfl_xor(dt[r], m);
    }
  }
  if (lr == 0){
    #pragma unroll
    for (int r=0;r<4;r++)
      scores[row0 + 4*lq + r] = dt[r] / fmaxf(sqrtf(ss[r]), 1e-12f);
  }
}

// ---------------- K2: per-batch exact top-64 via 8-bit radix select -----------------
__global__ __launch_bounds__(1024) void dsa_topk(const float* __restrict__ scores,
                                                 int* __restrict__ idxo){
  const int b = blockIdx.x, tid = threadIdx.x;
  const float* s = scores + b*NB;
  const int base = tid*16;
  unsigned key[16];
  #pragma unroll
  for (int i=0;i<16;i+=4){
    f32x4 f = *(const f32x4*)(s + base + i);
    #pragma unroll
    for (int c=0;c<4;c++){
      unsigned u = __float_as_uint(f[c]);
      key[i+c] = (u & 0x80000000u) ? ~u : (u | 0x80000000u);  // ascending uint order
    }
  }

  __shared__ unsigned bins[256];
  __shared__ unsigned sh_pref, sh_R;
  __shared__ int selIdx[64];
  __shared__ int eqIdx[256];
  __shared__ unsigned selCnt, eqCnt;

  unsigned prefix = 0, R = 64;
  for (int pass=0; pass<4; ++pass){
    const int shift = 24 - pass*8;
    if (tid < 256) bins[tid] = 0;
    __syncthreads();
    #pragma unroll
    for (int i=0;i<16;i++){
      unsigned k = key[i];
      bool ok;
      if (pass == 0) ok = true;
      else           ok = ((k >> (shift+8)) == prefix);
      if (ok) atomicAdd(&bins[(k >> shift) & 255u], 1u);
    }
    __syncthreads();
    if (tid < 64){
      unsigned c0 = bins[tid*4+0], c1 = bins[tid*4+1];
      unsigned c2 = bins[tid*4+2], c3 = bins[tid*4+3];
      unsigned gs = c0+c1+c2+c3;
      unsigned suf = gs;                       // inclusive suffix sum over 64 groups
      #pragma unroll
      for (int m=1;m<64;m<<=1){
        unsigned o = __shfl_down(suf, m);
        if (tid + m < 64) suf += o;
      }
      unsigned above = suf - gs;               // strictly-above-this-group count
      if (above < R && R <= suf){              // exactly one lane
        unsigned a3 = above;
        unsigned a2 = a3 + c3;
        unsigned a1 = a2 + c2;
        unsigned a0 = a1 + c1;
        unsigned bb, ab;
        if      (R <= a3 + c3){ bb = 3; ab = a3; }
        else if (R <= a2 + c2){ bb = 2; ab = a2; }
        else if (R <= a1 + c1){ bb = 1; ab = a1; }
        else                  { bb = 0; ab = a0; }
        sh_pref = (prefix << 8) | (tid*4 + bb);
        sh_R = R - ab;
      }
    }
    __syncthreads();
    prefix = sh_pref; R = sh_R;
    __syncthreads();
  }
  // prefix == exact key of 64th-largest; need R of the equal keys (smallest indices)
  if (tid == 0){ selCnt = 0; eqCnt = 0; }
  __syncthreads();
  #pragma unroll
  for (int i=0;i<16;i++){
    unsigned k = key[i];
    if (k > prefix){
      selIdx[atomicAdd(&selCnt, 1u)] = base + i;
    } else if (k == prefix){
      unsigned p = atomicAdd(&eqCnt, 1u);
      if (p < 256) eqIdx[p] = base + i;
    }
  }
  __syncthreads();
  if (tid == 0){
    unsigned n = eqCnt < 256u ? eqCnt : 256u;
    unsigned have = selCnt;
    for (unsigned r2 = 0; r2 < R; ++r2){
      int best = 0x7fffffff, bi = -1;
      for (unsigned e=0; e<n; e++)
        if (eqIdx[e] < best){ best = eqIdx[e]; bi = (int)e; }
      selIdx[have + r2] = best;
      eqIdx[bi] = 0x7fffffff;
    }
  }
  __syncthreads();
  if (tid < 64){                    // wave-0 bitonic sort ascending
    int x = selIdx[tid];
    #pragma unroll
    for (int size=2; size<=64; size<<=1){
      #pragma unroll
      for (int stride=size>>1; stride>0; stride>>=1){
        int ox = __shfl_xor(x, stride);
        bool up = ((tid & size) == 0);
        bool takeMin = (((tid & stride) == 0) == up);
        int mn = x < ox ? x : ox, mx = x < ox ? ox : x;
        x = takeMin ? mn : mx;
      }
    }
    idxo[b*64 + tid] = x;
  }
}

// ---------------- K3: fused per-batch tail: gather+LN+QKV+attention+Wo+enh ----------
__global__ __launch_bounds__(512) void dsa_tail(
    const float* __restrict__ a, const float* __restrict__ mq, const int* __restrict__ idx,
    const float* __restrict__ lnw, const float* __restrict__ lnb,
    const float* __restrict__ Wq, const float* __restrict__ bq,
    const float* __restrict__ Wk, const float* __restrict__ bk,
    const float* __restrict__ Wv, const float* __restrict__ bv,
    const float* __restrict__ Wo, const float* __restrict__ bo,
    float* __restrict__ enh)
{
  __shared__ float xln[80][64];
  __shared__ float qS[80][64];
  __shared__ float vS[80][68];     // padded: PV 4-group read -> 2-way (free)
  __shared__ float kT[64][81];     // K transposed, padded
  __shared__ float oS[80][64];
  __shared__ float WoS[64][64];
  __shared__ float rowbuf[8][84];  // per-wave prob row
  __shared__ int   sidx[64];

  const int b = blockIdx.x, tid = threadIdx.x;
  const int w = tid >> 6, lane = tid & 63;

  if (tid < 64) sidx[tid] = idx[b*64 + tid];
  for (int e = tid; e < 4096; e += 512) WoS[e>>6][e&63] = Wo[e];  // overlap with P0
  __syncthreads();

  // ---- P0: gather comb rows + layernorm (10 rows per wave, loads prefetched) ----
  {
    float lw = lnw[lane], lb = lnb[lane];
    float vals[10];
    #pragma unroll
    for (int i=0;i<10;i++){
      int s = w + 8*i;
      vals[i] = (s < 16) ? mq[s*64 + lane]
                         : a[((size_t)b*NB + sidx[s-16])*64 + lane];
    }
    #pragma unroll
    for (int i=0;i<10;i++){
      int s = w + 8*i;
      float val = vals[i];
      float sm = val, sq = val*val;
      #pragma unroll
      for (int m=1;m<64;m<<=1){ sm += __shfl_xor(sm,m); sq += __shfl_xor(sq,m); }
      float mu  = sm * (1.0f/64.0f);
      float var = sq * (1.0f/64.0f) - mu*mu;
      xln[s][lane] = (val - mu) * rsqrtf(var + 1e-5f) * lw + lb;
    }
  }
  __syncthreads();

  // ---- P1: QKV projections. W column in registers per lane. ----
  #pragma unroll 1
  for (int m = 0; m < 3; ++m){
    const float* Wm = (m==0) ? Wq : (m==1) ? Wk : Wv;
    const float* bm = (m==0) ? bq : (m==1) ? bk : bv;
    float wreg[64];
    #pragma unroll
    for (int c=0;c<64;c++) wreg[c] = Wm[c*64 + lane];
    float bias = bm[lane];
    #pragma unroll 1
    for (int s = w; s < 80; s += 8){
      float accv = bias;
      #pragma unroll
      for (int c4=0;c4<16;c4++){
        f32x4 x4 = *(const f32x4*)&xln[s][c4*4];
        accv += x4[0]*wreg[c4*4+0] + x4[1]*wreg[c4*4+1]
              + x4[2]*wreg[c4*4+2] + x4[3]*wreg[c4*4+3];
      }
      if (m==0)      qS[s][lane]  = accv;
      else if (m==1) kT[lane][s]  = accv;
      else           vS[s][lane]  = accv;
    }
  }
  __syncthreads();

  // ---- P2: fused scores+softmax+PV. Wave pair per head; rows 16..79 only. ----
  {
    const int h = w >> 1, h16 = h*16;
    const int i0 = 16 + (w & 1)*32;
    const int jj = lane >> 4, dd = lane & 15;
    #pragma unroll 2
    for (int ii = 0; ii < 32; ++ii){
      int i = i0 + ii;
      float v0 = 0.f, v1 = 0.f;
      #pragma unroll
      for (int d=0; d<16; ++d){
        float qd = qS[i][h16+d];
        v0 = fmaf(qd, kT[h16+d][lane],    v0);
        v1 = fmaf(qd, kT[h16+d][64 + dd], v1);
      }
      v0 *= 0.25f; v1 *= 0.25f;
      float mx = fmaxf(v0, v1);
      #pragma unroll
      for (int m2=1;m2<64;m2<<=1) mx = fmaxf(mx, __shfl_xor(mx,m2));
      float e0 = expf(v0 - mx);
      float e1 = expf(v1 - mx);
      float sm = e0 + ((lane < 16) ? e1 : 0.f);
      #pragma unroll
      for (int m2=1;m2<64;m2<<=1) sm += __shfl_xor(sm,m2);
      float inv = 1.0f / sm;
      rowbuf[w][lane] = e0 * inv;
      if (lane < 16) rowbuf[w][64+dd] = e1 * inv;
      // PV partials: lane = (jj,dd); same-wave LDS ordering guarantees visibility
      float part = 0.f;
      #pragma unroll
      for (int tt=0; tt<20; ++tt){
        int j = jj*20 + tt;
        part = fmaf(rowbuf[w][j], vS[j][h16+dd], part);
      }
      part += __shfl_xor(part, 16);
      part += __shfl_xor(part, 32);
      if (lane < 16) oS[i][h16+dd] = part;
    }
  }
  __syncthreads();

  // ---- P3: enh = comb_sparse + o @ Wo + bo ----
  for (int e = tid; e < 4096; e += 512){
    int s16 = e >> 6, cc = e & 63;
    float accv = bo[cc];
    #pragma unroll
    for (int d4=0; d4<16; ++d4){
      f32x4 o4 = *(const f32x4*)&oS[16+s16][d4*4];
      accv += o4[0]*WoS[d4*4+0][cc] + o4[1]*WoS[d4*4+1][cc]
            + o4[2]*WoS[d4*4+2][cc] + o4[3]*WoS[d4*4+3][cc];
    }
    float cmb = a[((size_t)b*NB + sidx[s16])*64 + cc];
    enh[(b*64 + s16)*64 + cc] = cmb + accv;
  }
}

// ---------------- K4: out[b, idx[j], :] += gamma * (enh[j] @ Wu) --------------------
__global__ __launch_bounds__(256) void dsa_scatter(
    const float* __restrict__ enh, const float* __restrict__ Wu,
    const float* __restrict__ gam, const int* __restrict__ idx,
    float* __restrict__ out)
{
  int blk = blockIdx.x;
  int b = blk >> 6, j = blk & 63;
  int tid = threadIdx.x;
  __shared__ float er[64];
  if (tid < 64) er[tid] = enh[(b*64+j)*64 + tid];
  __syncthreads();
  int n = idx[b*64 + j];
  float gamma = gam[0];
  int c0 = tid*4;
  float ax=0.f, ay=0.f, az=0.f, aw=0.f;
  #pragma unroll 8
  for (int d=0; d<64; ++d){
    float ev = er[d];
    f32x4 wr = *(const f32x4*)(Wu + d*CDIM + c0);
    ax += ev*wr[0]; ay += ev*wr[1]; az += ev*wr[2]; aw += ev*wr[3];
  }
  float* op = out + ((size_t)b*NB + n)*CDIM + c0;
  f32x4 cu = *(f32x4*)op;
  cu[0] += gamma*ax; cu[1] += gamma*ay; cu[2] += gamma*az; cu[3] += gamma*aw;
  *(f32x4*)op = cu;
}

extern "C" void kernel_launch(void* const* d_in, const int* in_sizes, int n_in,
                              void* d_out, int out_size, void* d_ws, size_t ws_size,
                              hipStream_t stream) {
  const float* X    = (const float*)d_in[0];
  const float* tf   = (const float*)d_in[1];
  const float* Wd   = (const float*)d_in[2];
  const float* bd   = (const float*)d_in[3];
  const float* Wu   = (const float*)d_in[4];
  const float* bu   = (const float*)d_in[5];
  const float* mq   = (const float*)d_in[6];
  const float* Wq   = (const float*)d_in[7];
  const float* bq   = (const float*)d_in[8];
  const float* Wk   = (const float*)d_in[9];
  const float* bk   = (const float*)d_in[10];
  const float* Wv   = (const float*)d_in[11];
  const float* bv   = (const float*)d_in[12];
  const float* Wo   = (const float*)d_in[13];
  const float* bo   = (const float*)d_in[14];
  const float* lnw  = (const float*)d_in[15];
  const float* lnb  = (const float*)d_in[16];
  const float* gam  = (const float*)d_in[17];
  float* out = (float*)d_out;

  float* ws_a               = (float*)d_ws;                 // 65536*64
  unsigned short* ws_wf     = (unsigned short*)(ws_a + (size_t)NROWS*DDIM);
  float* ws_scores          = (float*)(ws_wf + 64*CDIM);    // 65536
  float* ws_seln            = ws_scores + NROWS;            // 256
  float* ws_gbu             = ws_seln + 256;                // 1024
  int*   ws_idx             = (int*)(ws_gbu + 1024);        // 256
  float* ws_enh             = (float*)(ws_idx + 256);       // 4*64*64

  dsa_prep   <<<33,   256, 0, stream>>>(Wd, tf, bu, gam, ws_wf, ws_seln, ws_gbu);
  dsa_main   <<<1024, 256, 0, stream>>>(X, ws_wf, bd, ws_gbu, ws_seln,
                                        out, ws_a, ws_scores);
  dsa_topk   <<<4,   1024, 0, stream>>>(ws_scores, ws_idx);
  dsa_tail   <<<4,    512, 0, stream>>>(ws_a, mq, ws_idx, lnw, lnb,
                                        Wq, bq, Wk, bk, Wv, bv, Wo, bo, ws_enh);
  dsa_scatter<<<256,  256, 0, stream>>>(ws_enh, Wu, gam, ws_idx, out);
}